// Round 23
// baseline (145.520 us; speedup 1.0000x reference)
//
#include <hip/hip_runtime.h>

#define NDIM 2048
#define FDIM 64
#define KDIM 8
#define BDIM 32
#define TN   16     // tile rows (n)
#define TM   128    // tile cols (m) -> acc[8][2] = 64 VGPR
#define BFROW 72    // bf16 elems per staging row (64 + 8 pad)
#define PROW  132   // f32 elems per epilogue-panel row (128 + 4)
#define PLANES 4    // b-planes per epilogue pass
#define NTILE 4     // tiles per persistent block (512 blocks = 2/CU, 1 round)

typedef __attribute__((ext_vector_type(8))) short short8;
typedef __attribute__((ext_vector_type(4))) float f32x4;

static __device__ __forceinline__ unsigned short f2bf(float x) {
    unsigned u = __float_as_uint(x);                 // RNE to bf16
    return (unsigned short)((u + 0x7fffu + ((u >> 16) & 1u)) >> 16);
}

// ---------------------------------------------------------------------------
// R23 = R22 (best PASS, 108.7us) with three coupled scheduling fixes:
//  (1) cov barriers are lgkm-only (R22's __syncthreads drained vmcnt(0) --
//      killing the prev-tile store overlap at each tile start and draining
//      the k+1 prefetch at every k);
//  (2) cov LDS double-buffered (An/Am x2, 41.5KB union, 2 blocks/CU kept):
//      ONE barrier per k (write buf[k&1] -> barrier -> read buf[k&1]; writes
//      to the other buffer can't conflict; next barrier orders reuse);
//  (3) k=7's idle prefetch slot issues tile tt+1's k=0 loads (prologue
//      latency hidden under MFMA + epilogue).
// Invariants: persistent 512 grid (R20), reg-prefetch staging (R22), staged
// bf16 LDS cov (R17), full k-unroll + static indexing (rule #20), SCALAR mix
// only (f32x4 vector-mix = miscompile R6/R7/R9), NT stores (R16), epilogue
// verbatim R20.
// ---------------------------------------------------------------------------
__global__ __launch_bounds__(256, 2) void rfm_fused_mfma(
    const float* __restrict__ p, const float* __restrict__ L,
    const float* __restrict__ sr, float* __restrict__ out)
{
    __shared__ float pl[BDIM * KDIM];
    __shared__ __align__(16) char smem[2 * (TN + TM) * BFROW * 2];  // 41472 B

    unsigned short* const An0 = (unsigned short*)smem;
    unsigned short* const Am0 = An0 + TN * BFROW;
    unsigned short* const An1 = Am0 + TM * BFROW;
    unsigned short* const Am1 = An1 + TN * BFROW;
    float* const Parr0 = (float*)smem;          // epilogue panels (33792 B)
    float* const Parr1 = Parr0 + TN * PROW;
    float* const Parr2 = Parr1 + TN * PROW;
    float* const Parr3 = Parr2 + TN * PROW;

    const int t  = threadIdx.x;
    const int lane = t & 63;
    const int w   = t >> 6;        // wave 0..3: cols w*32..w*32+31
    const int l15 = lane & 15;
    const int l4  = lane >> 4;     // 0..3

    pl[t] = p[t];                  // visible after the first cov barrier

    const int sa_row = t >> 4;            // An row 0..15
    const int sa_fc  = (t & 15) << 2;     // f column (float4)
    const int bid = (int)blockIdx.x;

    // ---- prologue: load (tile 0, k=0) into prefetch registers ----
    float4 pva;
    float4 pvb[8];
    {
        const int m0p = (bid & 15) * TM;
        const int n0p = (bid >> 4) * TN;
        pva = *(const float4*)&L[(size_t)(n0p + sa_row) * FDIM + sa_fc];
        #pragma unroll
        for (int r = 0; r < 8; ++r) {
            const int idx = t + r * 256;
            pvb[r] = *(const float4*)
                &L[(size_t)(m0p + (idx >> 4)) * FDIM + ((idx & 15) << 2)];
        }
    }

    #pragma unroll 1
    for (int tt = 0; tt < NTILE; ++tt) {
        const int tile = bid + tt * 512;   // 0..2047
        const int m0 = (tile & 15) * TM;
        const int n0 = (tile >> 4) * TN;

        f32x4 acc[KDIM][2];
        #pragma unroll
        for (int k = 0; k < KDIM; ++k)
            #pragma unroll
            for (int j = 0; j < 2; ++j) acc[k][j] = (f32x4){0.f, 0.f, 0.f, 0.f};

        // ---- 1) cov: dbuf, 1 lgkm-barrier/k, reg-prefetch next ----
        #pragma unroll
        for (int k = 0; k < KDIM; ++k) {
            unsigned short* const Anb = (k & 1) ? An1 : An0;
            unsigned short* const Amb = (k & 1) ? Am1 : Am0;

            // stage current k from prefetch registers (pure ds_write)
            {
                ushort4 ua;
                ua.x = f2bf(pva.x); ua.y = f2bf(pva.y);
                ua.z = f2bf(pva.z); ua.w = f2bf(pva.w);
                *(ushort4*)&Anb[sa_row * BFROW + sa_fc] = ua;
            }
            #pragma unroll
            for (int r = 0; r < 8; ++r) {
                const int idx = t + r * 256;
                ushort4 ub;
                ub.x = f2bf(pvb[r].x); ub.y = f2bf(pvb[r].y);
                ub.z = f2bf(pvb[r].z); ub.w = f2bf(pvb[r].w);
                *(ushort4*)&Amb[(idx >> 4) * BFROW + ((idx & 15) << 2)] = ub;
            }

            // issue next prefetch: k+1 of this tile, or k=0 of next tile
            if (k + 1 < KDIM) {
                const float* Lk1 = L + (size_t)(k + 1) * (NDIM * FDIM);
                pva = *(const float4*)&Lk1[(size_t)(n0 + sa_row) * FDIM + sa_fc];
                #pragma unroll
                for (int r = 0; r < 8; ++r) {
                    const int idx = t + r * 256;
                    pvb[r] = *(const float4*)
                        &Lk1[(size_t)(m0 + (idx >> 4)) * FDIM + ((idx & 15) << 2)];
                }
            } else if (tt + 1 < NTILE) {
                const int tile2 = bid + (tt + 1) * 512;
                const int m0b = (tile2 & 15) * TM;
                const int n0b = (tile2 >> 4) * TN;
                pva = *(const float4*)&L[(size_t)(n0b + sa_row) * FDIM + sa_fc];
                #pragma unroll
                for (int r = 0; r < 8; ++r) {
                    const int idx = t + r * 256;
                    pvb[r] = *(const float4*)
                        &L[(size_t)(m0b + (idx >> 4)) * FDIM + ((idx & 15) << 2)];
                }
            }

            // lgkm-only barrier: my ds_writes done; k-2's reads of this buf
            // were lgkm-complete at the previous barrier. NT stores and
            // global prefetch stay in flight.
            asm volatile("s_waitcnt lgkmcnt(0)" ::: "memory");
            __builtin_amdgcn_s_barrier();
            __builtin_amdgcn_sched_barrier(0);

            short8 af[2], bv[2][2];
            #pragma unroll
            for (int s = 0; s < 2; ++s)
                af[s] = *(const short8*)&Anb[l15 * BFROW + s * 32 + l4 * 8];
            #pragma unroll
            for (int j = 0; j < 2; ++j)
                #pragma unroll
                for (int s = 0; s < 2; ++s)
                    bv[j][s] = *(const short8*)
                        &Amb[(w * 32 + j * 16 + l15) * BFROW + s * 32 + l4 * 8];
            #pragma unroll
            for (int j = 0; j < 2; ++j)
                #pragma unroll
                for (int s = 0; s < 2; ++s)
                    acc[k][j] = __builtin_amdgcn_mfma_f32_16x16x32_bf16(
                        af[s], bv[j][s], acc[k][j], 0, 0, 0);
        }

        // Diagonal: D row = n-local = l4*4+reg, col = m-local = w*32+j*16+l15.
        #pragma unroll
        for (int j = 0; j < 2; ++j)
            #pragma unroll
            for (int reg = 0; reg < 4; ++reg) {
                const int gn = n0 + l4 * 4 + reg;
                const int gm = m0 + w * 32 + j * 16 + l15;
                if (gn == gm) {
                    #pragma unroll
                    for (int k = 0; k < KDIM; ++k) {
                        const float q = sr[k * NDIM + gn];
                        acc[k][j][reg] += q * q;
                    }
                }
            }

        // all frag reads done before epilogue overwrites the buffers
        asm volatile("s_waitcnt lgkmcnt(0)" ::: "memory");
        __builtin_amdgcn_s_barrier();
        __builtin_amdgcn_sched_barrier(0);

        // ---- 2) epilogue: 4 planes/pass x 8 passes (verbatim R20) ----
        const size_t NN = (size_t)NDIM * NDIM;
        float* const Parr[PLANES] = { Parr0, Parr1, Parr2, Parr3 };
        const int scr = l4 * 4;                 // scatter row base (+reg)
        const int scc = w * 32 + l15;           // scatter col base (+j*16)
        const int rbrow = t >> 5;               // readback row 0..7 (and +8)
        const int rbc4  = (t & 31) * 4;         // readback col 0..124
        float* const obase = out + (size_t)n0 * NDIM + m0 + rbc4;

        #pragma unroll 1
        for (int b = 0; b < BDIM; b += PLANES) {
            #pragma unroll
            for (int u = 0; u < PLANES; ++u) {
                float pb[KDIM];
                #pragma unroll
                for (int k = 0; k < KDIM; ++k) pb[k] = pl[(b + u) * KDIM + k];
                float* const Pu = Parr[u];
                #pragma unroll
                for (int j = 0; j < 2; ++j)
                    #pragma unroll
                    for (int reg = 0; reg < 4; ++reg) {
                        float v = 0.0f;
                        #pragma unroll
                        for (int k = 0; k < KDIM; ++k)
                            v += pb[k] * acc[k][j][reg];
                        Pu[(scr + reg) * PROW + scc + j * 16] = v;
                    }
            }
            asm volatile("s_waitcnt lgkmcnt(0)" ::: "memory");  // ds_writes done
            __builtin_amdgcn_s_barrier();
            __builtin_amdgcn_sched_barrier(0);

            #pragma unroll
            for (int u = 0; u < PLANES; ++u) {
                const float* const Pu = Parr[u];
                const size_t boff = (size_t)(b + u) * NN;
                #pragma unroll
                for (int rr = 0; rr < 2; ++rr) {
                    const int row = rbrow + 8 * rr;
                    const f32x4 wv = *(const f32x4*)&Pu[row * PROW + rbc4];
                    __builtin_nontemporal_store(wv,
                        (f32x4*)(obase + boff + (size_t)row * NDIM));
                }
            }
            asm volatile("s_waitcnt lgkmcnt(0)" ::: "memory");  // ds_reads done
            __builtin_amdgcn_s_barrier();            // safe to overwrite / next tile
            __builtin_amdgcn_sched_barrier(0);
        }
    }
}

extern "C" void kernel_launch(void* const* d_in, const int* in_sizes, int n_in,
                              void* d_out, int out_size, void* d_ws, size_t ws_size,
                              hipStream_t stream)
{
    const float* p  = (const float*)d_in[0];   // (B,K) = (32,8)
    const float* L  = (const float*)d_in[1];   // (K,N,F) = (8,2048,64)
    const float* sr = (const float*)d_in[2];   // (K,N)   = (8,2048)
    float* out = (float*)d_out;                // (B,N,N) = (32,2048,2048)

    hipLaunchKernelGGL(rfm_fused_mfma, dim3(512), dim3(256), 0, stream,
                       p, L, sr, out);
}

// Round 24
// 108.379 us; speedup vs baseline: 1.3427x; 1.3427x over previous
//
#include <hip/hip_runtime.h>

#define NDIM 2048
#define FDIM 64
#define KDIM 8
#define BDIM 32
#define TN   16     // tile rows (n)
#define TM   128    // tile cols (m) -> acc[8][2] = 64 VGPR
#define BFROW 72    // bf16 elems per staging row (64 + 8 pad)
#define PROW  132   // f32 elems per epilogue-panel row (128 + 4)
#define PLANES 4    // b-planes per epilogue pass
#define NTILE 4     // tiles per persistent block (512 blocks = 2/CU, 1 round)

typedef __attribute__((ext_vector_type(8))) short short8;
typedef __attribute__((ext_vector_type(4))) float f32x4;

static __device__ __forceinline__ unsigned short f2bf(float x) {
    unsigned u = __float_as_uint(x);                 // RNE to bf16
    return (unsigned short)((u + 0x7fffu + ((u >> 16) & 1u)) >> 16);
}

// ---------------------------------------------------------------------------
// R24 = R22 (best PASS, 108.7us) with ONE change: cov LDS double-buffer.
// Iter k: ds_write buf[k&1] -> __syncthreads (ONE barrier/k, 9/tile vs 16) ->
// issue prefetch k+1 -> frag-read buf[k&1] + MFMA. Reads of iter k are
// per-wave drained by the __syncthreads of iter k+1, before buf[k&1] is
// rewritten at k+2 -> safe. __syncthreads (vmcnt-draining) KEPT: R23 proved
// lgkm-only cov barriers + deep NT-store queues regress 37us (store queue
// starves prefetch loads). Prefetch hiding window unchanged (issued after
// barrier, consumed by next iter's ds_write).
// Invariants: persistent 512 grid (R20), reg-prefetch staging (R22), staged
// bf16 LDS cov (R17), full k-unroll + static idx (rule #20), SCALAR mix only
// (f32x4 vector-mix = miscompile R6/R7/R9), NT stores (R16), epilogue
// verbatim R20/R22.
// ---------------------------------------------------------------------------
__global__ __launch_bounds__(256, 2) void rfm_fused_mfma(
    const float* __restrict__ p, const float* __restrict__ L,
    const float* __restrict__ sr, float* __restrict__ out)
{
    __shared__ float pl[BDIM * KDIM];
    __shared__ __align__(16) char smem[2 * (TN + TM) * BFROW * 2];  // 41472 B

    unsigned short* const An0 = (unsigned short*)smem;
    unsigned short* const Am0 = An0 + TN * BFROW;
    unsigned short* const An1 = Am0 + TM * BFROW;
    unsigned short* const Am1 = An1 + TN * BFROW;
    float* const Parr0 = (float*)smem;          // epilogue panels (33792 B)
    float* const Parr1 = Parr0 + TN * PROW;
    float* const Parr2 = Parr1 + TN * PROW;
    float* const Parr3 = Parr2 + TN * PROW;

    const int t  = threadIdx.x;
    const int lane = t & 63;
    const int w   = t >> 6;        // wave 0..3: cols w*32..w*32+31
    const int l15 = lane & 15;
    const int l4  = lane >> 4;     // 0..3

    pl[t] = p[t];                  // covered by the first cov __syncthreads

    const int sa_row = t >> 4;            // An row 0..15
    const int sa_fc  = (t & 15) << 2;     // f column (float4)

    #pragma unroll 1
    for (int tt = 0; tt < NTILE; ++tt) {
        const int tile = (int)blockIdx.x + tt * 512;   // 0..2047
        const int m0 = (tile & 15) * TM;
        const int n0 = (tile >> 4) * TN;

        f32x4 acc[KDIM][2];
        #pragma unroll
        for (int k = 0; k < KDIM; ++k)
            #pragma unroll
            for (int j = 0; j < 2; ++j) acc[k][j] = (f32x4){0.f, 0.f, 0.f, 0.f};

        // ---- cov prologue: load k=0 into registers (verbatim R22) ----
        float4 pva;
        float4 pvb[8];
        {
            pva = *(const float4*)&L[(size_t)(n0 + sa_row) * FDIM + sa_fc];
            #pragma unroll
            for (int r = 0; r < 8; ++r) {
                const int idx = t + r * 256;
                pvb[r] = *(const float4*)
                    &L[(size_t)(m0 + (idx >> 4)) * FDIM + ((idx & 15) << 2)];
            }
        }

        // ---- 1) cov: dbuf, ONE __syncthreads per k, reg-prefetch k+1 ----
        #pragma unroll
        for (int k = 0; k < KDIM; ++k) {
            unsigned short* const Anb = (k & 1) ? An1 : An0;
            unsigned short* const Amb = (k & 1) ? Am1 : Am0;

            // stage current k from prefetch registers (pure ds_write)
            {
                ushort4 ua;
                ua.x = f2bf(pva.x); ua.y = f2bf(pva.y);
                ua.z = f2bf(pva.z); ua.w = f2bf(pva.w);
                *(ushort4*)&Anb[sa_row * BFROW + sa_fc] = ua;
            }
            #pragma unroll
            for (int r = 0; r < 8; ++r) {
                const int idx = t + r * 256;
                ushort4 ub;
                ub.x = f2bf(pvb[r].x); ub.y = f2bf(pvb[r].y);
                ub.z = f2bf(pvb[r].z); ub.w = f2bf(pvb[r].w);
                *(ushort4*)&Amb[(idx >> 4) * BFROW + ((idx & 15) << 2)] = ub;
            }
            __syncthreads();   // buf[k&1] ready; also drains vmem queue

            // issue k+1 loads NOW; latency hides under frag reads + MFMA
            if (k + 1 < KDIM) {
                const float* Lk1 = L + (size_t)(k + 1) * (NDIM * FDIM);
                pva = *(const float4*)&Lk1[(size_t)(n0 + sa_row) * FDIM + sa_fc];
                #pragma unroll
                for (int r = 0; r < 8; ++r) {
                    const int idx = t + r * 256;
                    pvb[r] = *(const float4*)
                        &Lk1[(size_t)(m0 + (idx >> 4)) * FDIM + ((idx & 15) << 2)];
                }
            }

            short8 af[2], bv[2][2];
            #pragma unroll
            for (int s = 0; s < 2; ++s)
                af[s] = *(const short8*)&Anb[l15 * BFROW + s * 32 + l4 * 8];
            #pragma unroll
            for (int j = 0; j < 2; ++j)
                #pragma unroll
                for (int s = 0; s < 2; ++s)
                    bv[j][s] = *(const short8*)
                        &Amb[(w * 32 + j * 16 + l15) * BFROW + s * 32 + l4 * 8];
            #pragma unroll
            for (int j = 0; j < 2; ++j)
                #pragma unroll
                for (int s = 0; s < 2; ++s)
                    acc[k][j] = __builtin_amdgcn_mfma_f32_16x16x32_bf16(
                        af[s], bv[j][s], acc[k][j], 0, 0, 0);
            // no trailing barrier: buf[(k+1)&1] writes don't touch buf[k&1];
            // next __syncthreads (iter k+1) drains these reads before k+2
            // rewrites this buffer.
        }

        // Diagonal: D row = n-local = l4*4+reg, col = m-local = w*32+j*16+l15.
        #pragma unroll
        for (int j = 0; j < 2; ++j)
            #pragma unroll
            for (int reg = 0; reg < 4; ++reg) {
                const int gn = n0 + l4 * 4 + reg;
                const int gm = m0 + w * 32 + j * 16 + l15;
                if (gn == gm) {
                    #pragma unroll
                    for (int k = 0; k < KDIM; ++k) {
                        const float q = sr[k * NDIM + gn];
                        acc[k][j][reg] += q * q;
                    }
                }
            }

        __syncthreads();   // all frag reads done; epilogue may overwrite smem

        // ---- 2) epilogue: 4 planes/pass x 8 passes (verbatim R22) ----
        const size_t NN = (size_t)NDIM * NDIM;
        float* const Parr[PLANES] = { Parr0, Parr1, Parr2, Parr3 };
        const int scr = l4 * 4;                 // scatter row base (+reg)
        const int scc = w * 32 + l15;           // scatter col base (+j*16)
        const int rbrow = t >> 5;               // readback row 0..7 (and +8)
        const int rbc4  = (t & 31) * 4;         // readback col 0..124
        float* const obase = out + (size_t)n0 * NDIM + m0 + rbc4;

        #pragma unroll 1
        for (int b = 0; b < BDIM; b += PLANES) {
            #pragma unroll
            for (int u = 0; u < PLANES; ++u) {
                float pb[KDIM];
                #pragma unroll
                for (int k = 0; k < KDIM; ++k) pb[k] = pl[(b + u) * KDIM + k];
                float* const Pu = Parr[u];
                #pragma unroll
                for (int j = 0; j < 2; ++j)
                    #pragma unroll
                    for (int reg = 0; reg < 4; ++reg) {
                        float v = 0.0f;
                        #pragma unroll
                        for (int k = 0; k < KDIM; ++k)
                            v += pb[k] * acc[k][j][reg];
                        Pu[(scr + reg) * PROW + scc + j * 16] = v;
                    }
            }
            asm volatile("s_waitcnt lgkmcnt(0)" ::: "memory");  // ds_writes done
            __builtin_amdgcn_s_barrier();
            __builtin_amdgcn_sched_barrier(0);

            #pragma unroll
            for (int u = 0; u < PLANES; ++u) {
                const float* const Pu = Parr[u];
                const size_t boff = (size_t)(b + u) * NN;
                #pragma unroll
                for (int rr = 0; rr < 2; ++rr) {
                    const int row = rbrow + 8 * rr;
                    const f32x4 wv = *(const f32x4*)&Pu[row * PROW + rbc4];
                    __builtin_nontemporal_store(wv,
                        (f32x4*)(obase + boff + (size_t)row * NDIM));
                }
            }
            asm volatile("s_waitcnt lgkmcnt(0)" ::: "memory");  // ds_reads done
            __builtin_amdgcn_s_barrier();            // safe to overwrite / next tile
            __builtin_amdgcn_sched_barrier(0);
        }
    }
}

extern "C" void kernel_launch(void* const* d_in, const int* in_sizes, int n_in,
                              void* d_out, int out_size, void* d_ws, size_t ws_size,
                              hipStream_t stream)
{
    const float* p  = (const float*)d_in[0];   // (B,K) = (32,8)
    const float* L  = (const float*)d_in[1];   // (K,N,F) = (8,2048,64)
    const float* sr = (const float*)d_in[2];   // (K,N)   = (8,2048)
    float* out = (float*)d_out;                // (B,N,N) = (32,2048,2048)

    hipLaunchKernelGGL(rfm_fused_mfma, dim3(512), dim3(256), 0, stream,
                       p, L, sr, out);
}